// Round 16
// baseline (26.549 us; speedup 1.0000x reference)
//
#include <hip/hip_runtime.h>
#include <hip/hip_bf16.h>

#define BATCH 64
#define NADJ  512
#define F     128
#define CROP0 128
#define CROP1 384
#define CN    256
#define BN_EPS 1e-5f

typedef __attribute__((ext_vector_type(8))) short short8;
typedef __attribute__((ext_vector_type(4))) float f32x4;

__device__ __forceinline__ ushort f2bf(float x) {
  __hip_bfloat16 h = __float2bfloat16(x);  // RNE
  return *reinterpret_cast<ushort*>(&h);
}

__device__ __forceinline__ short8 cvt8(const float4 a, const float4 b) {
  short8 r;
  r[0] = (short)f2bf(a.x); r[1] = (short)f2bf(a.y);
  r[2] = (short)f2bf(a.z); r[3] = (short)f2bf(a.w);
  r[4] = (short)f2bf(b.x); r[5] = (short)f2bf(b.y);
  r[6] = (short)f2bf(b.z); r[7] = (short)f2bf(b.w);
  return r;
}

// ---------------------------------------------------------------------------
// KA v16: fused support+aggregate, f-half split -> 2 blocks/CU.
// Grid 512, 512 threads. Block = (batch b, f-half fh, quarter qt); all 8
// blocks of b on XCD (b&7): the fh=0/1 pair shares adj rows through L2.
// Per block: W^T(64f) -> LDS; S[b][:,fh] -> LDS stl[64][268] (chunk-wise,
// reg-pipelined staging); agg of 64 n-rows x 64 f with adj A-operand
// pre-issued 8+8 float4 (entry + agg-start) to stay under 128 VGPR.
// LDS 69.1KB -> 2 blocks/CU = 16 waves/CU; barrier stalls of one block
// are covered by the co-resident block.
// ---------------------------------------------------------------------------
__global__ __launch_bounds__(512, 4) void gcn_ka(
    const float* __restrict__ input, const float* __restrict__ adj,
    const float* __restrict__ W, const float* __restrict__ beta,
    float* __restrict__ out, float* __restrict__ Ocrop) {
  const int x = blockIdx.x & 7, y = blockIdx.x >> 3;
  const int b   = ((y >> 3) << 3) | x;  // batch (b&7 == x)
  const int sub = y & 7;
  const int fh  = sub >> 2;  // f-half (64 f)
  const int qt  = sub & 3;   // quarter (64 n-rows)
  __shared__ ushort wt[64][136];   // W^T half [fl][i]   17408 B
  __shared__ ushort ain[64][136];  // input chunk [m][i] 17408 B
  __shared__ ushort stl[64][268];  // S^T half [fl][m]   34304 B
  const int tid = threadIdx.x;
  const int l = tid & 63, w = tid >> 6;
  const int lr = l & 15, lg = l >> 4;

  // ---- pre-issue agg A-operand, first half (k 0..127): 8 x float4 ----
  const int n0  = qt * 64 + (w & 3) * 16;
  const float* a0 =
      adj + ((size_t)b * NADJ + CROP0 + n0 + lr) * NADJ + CROP0;
  float4 xregA[8];
#pragma unroll
  for (int ks = 0; ks < 4; ++ks) {
    const int k0 = ks * 32 + lg * 8;
    xregA[2 * ks]     = *reinterpret_cast<const float4*>(&a0[k0]);
    xregA[2 * ks + 1] = *reinterpret_cast<const float4*>(&a0[k0 + 4]);
  }

  // ---- beta-fill non-crop rows of out (independent stores) ----
  {
    const int gid = blockIdx.x * 512 + tid;  // [0, 262144)
#pragma unroll
    for (int q = 0; q < 2; ++q) {
      const int g2 = gid + q * 262144;  // [0, 524288) float4s
      const int c4 = (g2 & 31) * 4;
      const int rr = (g2 >> 5) & 255;
      const int bb = g2 >> 13;
      const int n  = rr < 128 ? rr : rr + 256;
      const float4 bv =
          *reinterpret_cast<const float4*>(&beta[(size_t)n * F + c4]);
      *reinterpret_cast<float4*>(&out[((size_t)bb * NADJ + n) * F + c4]) = bv;
    }
  }

  // ---- stage W^T half: 64 f x 128 i ----
  {
    const int i  = tid & 127;
    const int fg = (tid >> 7) * 16;
    const float* wr = &W[(size_t)i * F + fh * 64 + fg];
    float4 v[4];
#pragma unroll
    for (int q = 0; q < 4; ++q)
      v[q] = reinterpret_cast<const float4*>(wr)[q];
#pragma unroll
    for (int q = 0; q < 4; ++q) {
      wt[fg + q * 4 + 0][i] = f2bf(v[q].x);
      wt[fg + q * 4 + 1][i] = f2bf(v[q].y);
      wt[fg + q * 4 + 2][i] = f2bf(v[q].z);
      wt[fg + q * 4 + 3][i] = f2bf(v[q].w);
    }
  }

  // ---- S[b][:, f-half] in 4 m-chunks of 64, reg-pipelined staging ----
  const float* inb = input + ((size_t)b * NADJ + CROP0) * F;
  const int msub = (w & 3) * 16;    // wave m-subtile within chunk
  const int sfq  = (w >> 2) * 32;   // wave f-quarter within half
  const int ml0  = tid >> 5;        // staging row 0..15 (+q*16)
  const int ic4  = (tid & 31) * 4;  // staging col
  float4 pv[4];
#pragma unroll
  for (int q = 0; q < 4; ++q)
    pv[q] = *reinterpret_cast<const float4*>(
        &inb[(size_t)(ml0 + q * 16) * F + ic4]);

  for (int mc = 0; mc < CN; mc += 64) {
#pragma unroll
    for (int q = 0; q < 4; ++q)
      *reinterpret_cast<ushort4*>(&ain[ml0 + q * 16][ic4]) =
          make_ushort4(f2bf(pv[q].x), f2bf(pv[q].y), f2bf(pv[q].z),
                       f2bf(pv[q].w));
    __syncthreads();  // ain (and wt, first iter) visible
    if (mc + 64 < CN) {
#pragma unroll
      for (int q = 0; q < 4; ++q)
        pv[q] = *reinterpret_cast<const float4*>(
            &inb[(size_t)(mc + 64 + ml0 + q * 16) * F + ic4]);
    }
    f32x4 sacc[2] = {};
#pragma unroll
    for (int ks = 0; ks < 4; ++ks) {
      const int k0 = ks * 32 + lg * 8;
      const short8 av = *reinterpret_cast<const short8*>(&ain[msub + lr][k0]);
#pragma unroll
      for (int fi = 0; fi < 2; ++fi) {
        const short8 bv =
            *reinterpret_cast<const short8*>(&wt[sfq + fi * 16 + lr][k0]);
        sacc[fi] =
            __builtin_amdgcn_mfma_f32_16x16x32_bf16(av, bv, sacc[fi], 0, 0, 0);
      }
    }
#pragma unroll
    for (int fi = 0; fi < 2; ++fi)
      *reinterpret_cast<ushort4*>(
          &stl[sfq + fi * 16 + lr][mc + msub + lg * 4]) =
          make_ushort4(f2bf(sacc[fi][0]), f2bf(sacc[fi][1]),
                       f2bf(sacc[fi][2]), f2bf(sacc[fi][3]));
    __syncthreads();  // ain reads done; stl chunk visible
  }

  // ---- aggregation: issue second-half adj loads, then LDS+MFMA ----
  float4 xregB[8];
#pragma unroll
  for (int ks = 0; ks < 4; ++ks) {
    const int k0 = 128 + ks * 32 + lg * 8;
    xregB[2 * ks]     = *reinterpret_cast<const float4*>(&a0[k0]);
    xregB[2 * ks + 1] = *reinterpret_cast<const float4*>(&a0[k0 + 4]);
  }
  f32x4 acc[2] = {};
#pragma unroll
  for (int ks = 0; ks < 8; ++ks) {
    const int k0 = ks * 32 + lg * 8;
    const short8 av = (ks < 4)
                          ? cvt8(xregA[2 * ks], xregA[2 * ks + 1])
                          : cvt8(xregB[2 * (ks - 4)], xregB[2 * (ks - 4) + 1]);
#pragma unroll
    for (int fi = 0; fi < 2; ++fi) {
      const short8 bv =
          *reinterpret_cast<const short8*>(&stl[sfq + fi * 16 + lr][k0]);
      acc[fi] =
          __builtin_amdgcn_mfma_f32_16x16x32_bf16(av, bv, acc[fi], 0, 0, 0);
    }
  }
  // D: col(f)=lane&15, row(n)=4*(lane>>4)+reg
#pragma unroll
  for (int fi = 0; fi < 2; ++fi) {
    const int f = fh * 64 + sfq + fi * 16 + lr;
    const int n = n0 + lg * 4;
#pragma unroll
    for (int r = 0; r < 4; ++r)
      Ocrop[((size_t)b * CN + n + r) * F + f] = acc[fi][r];
  }
}

// ---------------------------------------------------------------------------
// KB: BN stats + normalize crop rows -> out.
// ---------------------------------------------------------------------------
__global__ __launch_bounds__(256) void gcn_kb(
    const float* __restrict__ Ocrop, float* __restrict__ out,
    const float* __restrict__ gamma, const float* __restrict__ beta) {
  __shared__ float s_l[256], s2_l[256], m_l[64], r_l[64];
  const int tid = threadIdx.x;
  const int jl = tid & 63, bg = tid >> 6;
  const int j  = blockIdx.x * 64 + jl;  // 0..32767 = nl*128+f
  const int nl = j >> 7, f = j & 127;
  const int nf = (CROP0 + nl) * F + f;
  const float* p = Ocrop + (size_t)j + (size_t)bg * 16 * CN * F;

  float x[16];
  float s = 0.f, s2 = 0.f;
#pragma unroll
  for (int bb = 0; bb < 16; ++bb) {
    x[bb] = p[(size_t)bb * CN * F];
    s += x[bb];
    s2 += x[bb] * x[bb];
  }
  s_l[tid]  = s;
  s2_l[tid] = s2;
  __syncthreads();
  if (tid < 64) {
    s  = s_l[jl] + s_l[64 + jl] + s_l[128 + jl] + s_l[192 + jl];
    s2 = s2_l[jl] + s2_l[64 + jl] + s2_l[128 + jl] + s2_l[192 + jl];
    const float mean = s * (1.f / BATCH);
    const float var  = s2 * (1.f / BATCH) - mean * mean;
    m_l[jl] = mean;
    r_l[jl] = rsqrtf(var + BN_EPS);
  }
  __syncthreads();
  const float mean = m_l[jl];
  const float a    = r_l[jl] * gamma[nf];
  const float c    = beta[nf] - mean * a;
#pragma unroll
  for (int bb = 0; bb < 16; ++bb)
    out[(size_t)nf + (size_t)(bg * 16 + bb) * NADJ * F] = x[bb] * a + c;
}

extern "C" void kernel_launch(void* const* d_in, const int* in_sizes, int n_in,
                              void* d_out, int out_size, void* d_ws,
                              size_t ws_size, hipStream_t stream) {
  const float* input = (const float*)d_in[0];
  const float* adj   = (const float*)d_in[1];
  const float* W     = (const float*)d_in[2];
  const float* gamma = (const float*)d_in[3];
  const float* beta  = (const float*)d_in[4];
  float* out = (float*)d_out;

  float* Ocrop = (float*)d_ws;  // 64*256*128 fp32 = 8.4 MB

  gcn_ka<<<512, 512, 0, stream>>>(input, adj, W, beta, out, Ocrop);
  gcn_kb<<<512, 256, 0, stream>>>(Ocrop, out, gamma, beta);
}

// Round 17
// 23.502 us; speedup vs baseline: 1.1296x; 1.1296x over previous
//
#include <hip/hip_runtime.h>
#include <hip/hip_bf16.h>

#define BATCH 64
#define NADJ  512
#define F     128
#define CROP0 128
#define CROP1 384
#define CN    256
#define BN_EPS 1e-5f

typedef __attribute__((ext_vector_type(8))) short short8;
typedef __attribute__((ext_vector_type(4))) float f32x4;

__device__ __forceinline__ ushort f2bf(float x) {
  __hip_bfloat16 h = __float2bfloat16(x);  // RNE
  return *reinterpret_cast<ushort*>(&h);
}

__device__ __forceinline__ float bf2f(ushort u) {
  const unsigned v = (unsigned)u << 16;
  float f;
  __builtin_memcpy(&f, &v, 4);
  return f;
}

__device__ __forceinline__ short8 cvt8(const float4 a, const float4 b) {
  short8 r;
  r[0] = (short)f2bf(a.x); r[1] = (short)f2bf(a.y);
  r[2] = (short)f2bf(a.z); r[3] = (short)f2bf(a.w);
  r[4] = (short)f2bf(b.x); r[5] = (short)f2bf(b.y);
  r[6] = (short)f2bf(b.z); r[7] = (short)f2bf(b.w);
  return r;
}

// ---------------------------------------------------------------------------
// KA v17 (R15 base + agg interleave + bf16 Ocrop).
// 256 blocks x 512 threads, 1 block/CU. Block = (batch b, quarter qt),
// 4 blocks/batch on XCD (b&7). Full S[b] -> LDS stl[128][268].
// Agg k-chunk (mc-64) interleaved into S-chunk iteration mc (stl visible
// after prior closing barrier); mc loop fully unrolled -> static xreg idx.
// adj A-operand (16 float4) pre-issued at entry; S staging reg-pipelined.
// ---------------------------------------------------------------------------
__global__ __launch_bounds__(512, 1) void gcn_ka(
    const float* __restrict__ input, const float* __restrict__ adj,
    const float* __restrict__ W, const float* __restrict__ beta,
    float* __restrict__ out, ushort* __restrict__ Ocrop) {
  const int x = blockIdx.x & 7, y = blockIdx.x >> 3;
  const int b  = ((y >> 2) << 3) | x;  // batch
  const int qt = y & 3;                // quarter (64 n-rows)
  __shared__ ushort wt[128][136];   // W^T [f][i]
  __shared__ ushort ain[64][136];   // input chunk [m][i]
  __shared__ ushort stl[128][268];  // S^T full [f][m], 536B row stride
  const int tid = threadIdx.x;
  const int l = tid & 63, w = tid >> 6;
  const int lr = l & 15, lg = l >> 4;

  // ---- pre-issue agg A-operand: 16 x float4 of adj ----
  const int n0  = qt * 64 + (w & 3) * 16;
  const int wf0 = (w >> 2) * 64;
  const float* a0 =
      adj + ((size_t)b * NADJ + CROP0 + n0 + lr) * NADJ + CROP0;
  float4 xreg[16];
#pragma unroll
  for (int ks = 0; ks < 8; ++ks) {
    const int k0 = ks * 32 + lg * 8;
    xreg[2 * ks]     = *reinterpret_cast<const float4*>(&a0[k0]);
    xreg[2 * ks + 1] = *reinterpret_cast<const float4*>(&a0[k0 + 4]);
  }

  // ---- beta-fill non-crop rows of out ----
  {
    const int gid = blockIdx.x * 512 + tid;
#pragma unroll
    for (int q = 0; q < 4; ++q) {
      const int g2 = gid + q * 131072;
      const int c4 = (g2 & 31) * 4;
      const int rr = (g2 >> 5) & 255;
      const int bb = g2 >> 13;
      const int n  = rr < 128 ? rr : rr + 256;
      const float4 bv =
          *reinterpret_cast<const float4*>(&beta[(size_t)n * F + c4]);
      *reinterpret_cast<float4*>(&out[((size_t)bb * NADJ + n) * F + c4]) = bv;
    }
  }

  // ---- stage W^T ----
  {
    const int i0 = tid & 63;
    const int fq = (tid >> 6) * 16;
#pragma unroll
    for (int ih = 0; ih < 2; ++ih) {
      const int i = i0 + ih * 64;
      const float* wr = &W[(size_t)i * F + fq];
      float4 v[4];
#pragma unroll
      for (int q = 0; q < 4; ++q)
        v[q] = reinterpret_cast<const float4*>(wr)[q];
#pragma unroll
      for (int q = 0; q < 4; ++q) {
        wt[fq + q * 4 + 0][i] = f2bf(v[q].x);
        wt[fq + q * 4 + 1][i] = f2bf(v[q].y);
        wt[fq + q * 4 + 2][i] = f2bf(v[q].z);
        wt[fq + q * 4 + 3][i] = f2bf(v[q].w);
      }
    }
  }

  // ---- S[b] in 4 m-chunks (fully unrolled) + interleaved agg ----
  const float* inb = input + ((size_t)b * NADJ + CROP0) * F;
  const int msub = (w & 3) * 16;
  const int sf0  = (w >> 2) * 64;
  const int ml0  = tid >> 5;
  const int ic4  = (tid & 31) * 4;
  float4 pv[4];
#pragma unroll
  for (int q = 0; q < 4; ++q)
    pv[q] = *reinterpret_cast<const float4*>(
        &inb[(size_t)(ml0 + q * 16) * F + ic4]);

  f32x4 acc[4] = {};
#pragma unroll
  for (int cc = 0; cc < 4; ++cc) {
    const int mc = cc * 64;
    // write prefetched input chunk to ain
#pragma unroll
    for (int q = 0; q < 4; ++q)
      *reinterpret_cast<ushort4*>(&ain[ml0 + q * 16][ic4]) =
          make_ushort4(f2bf(pv[q].x), f2bf(pv[q].y), f2bf(pv[q].z),
                       f2bf(pv[q].w));
    __syncthreads();  // ain (and wt on cc=0) visible
    // prefetch next chunk (overlaps MFMA below)
    if (cc < 3) {
#pragma unroll
      for (int q = 0; q < 4; ++q)
        pv[q] = *reinterpret_cast<const float4*>(
            &inb[(size_t)(mc + 64 + ml0 + q * 16) * F + ic4]);
    }
    // interleaved agg for previous chunk (stl visible since prior barrier)
    if (cc > 0) {
      const int kb0 = mc - 64;
#pragma unroll
      for (int ks2 = 0; ks2 < 2; ++ks2) {
        const int ks = (cc - 1) * 2 + ks2;  // static
        const int k0 = kb0 + ks2 * 32 + lg * 8;
        const short8 av = cvt8(xreg[2 * ks], xreg[2 * ks + 1]);
#pragma unroll
        for (int fi = 0; fi < 4; ++fi) {
          const short8 bv =
              *reinterpret_cast<const short8*>(&stl[wf0 + fi * 16 + lr][k0]);
          acc[fi] =
              __builtin_amdgcn_mfma_f32_16x16x32_bf16(av, bv, acc[fi], 0, 0, 0);
        }
      }
    }
    // S-compute for this chunk
    f32x4 sacc[4] = {};
#pragma unroll
    for (int ks = 0; ks < 4; ++ks) {
      const int k0 = ks * 32 + lg * 8;
      const short8 av = *reinterpret_cast<const short8*>(&ain[msub + lr][k0]);
#pragma unroll
      for (int fi = 0; fi < 4; ++fi) {
        const short8 bv =
            *reinterpret_cast<const short8*>(&wt[sf0 + fi * 16 + lr][k0]);
        sacc[fi] =
            __builtin_amdgcn_mfma_f32_16x16x32_bf16(av, bv, sacc[fi], 0, 0, 0);
      }
    }
#pragma unroll
    for (int fi = 0; fi < 4; ++fi)
      *reinterpret_cast<ushort4*>(
          &stl[sf0 + fi * 16 + lr][mc + msub + lg * 4]) =
          make_ushort4(f2bf(sacc[fi][0]), f2bf(sacc[fi][1]),
                       f2bf(sacc[fi][2]), f2bf(sacc[fi][3]));
    __syncthreads();  // ain reads done; stl chunk visible
  }

  // ---- final agg chunk (k 192..255) ----
#pragma unroll
  for (int ks2 = 0; ks2 < 2; ++ks2) {
    const int ks = 6 + ks2;
    const int k0 = 192 + ks2 * 32 + lg * 8;
    const short8 av = cvt8(xreg[2 * ks], xreg[2 * ks + 1]);
#pragma unroll
    for (int fi = 0; fi < 4; ++fi) {
      const short8 bv =
          *reinterpret_cast<const short8*>(&stl[wf0 + fi * 16 + lr][k0]);
      acc[fi] =
          __builtin_amdgcn_mfma_f32_16x16x32_bf16(av, bv, acc[fi], 0, 0, 0);
    }
  }

  // ---- store Ocrop (bf16): col(f)=lane&15, row(n)=4*(lane>>4)+reg ----
#pragma unroll
  for (int fi = 0; fi < 4; ++fi) {
    const int f = wf0 + fi * 16 + lr;
    const int n = n0 + lg * 4;
#pragma unroll
    for (int r = 0; r < 4; ++r)
      Ocrop[((size_t)b * CN + n + r) * F + f] = f2bf(acc[fi][r]);
  }
}

// ---------------------------------------------------------------------------
// KB: BN stats + normalize crop rows (bf16 Ocrop in, fp32 out).
// ---------------------------------------------------------------------------
__global__ __launch_bounds__(256) void gcn_kb(
    const ushort* __restrict__ Ocrop, float* __restrict__ out,
    const float* __restrict__ gamma, const float* __restrict__ beta) {
  __shared__ float s_l[256], s2_l[256], m_l[64], r_l[64];
  const int tid = threadIdx.x;
  const int jl = tid & 63, bg = tid >> 6;
  const int j  = blockIdx.x * 64 + jl;  // 0..32767 = nl*128+f
  const int nl = j >> 7, f = j & 127;
  const int nf = (CROP0 + nl) * F + f;
  const ushort* p = Ocrop + (size_t)j + (size_t)bg * 16 * CN * F;

  float x[16];
  float s = 0.f, s2 = 0.f;
#pragma unroll
  for (int bb = 0; bb < 16; ++bb) {
    x[bb] = bf2f(p[(size_t)bb * CN * F]);
    s += x[bb];
    s2 += x[bb] * x[bb];
  }
  s_l[tid]  = s;
  s2_l[tid] = s2;
  __syncthreads();
  if (tid < 64) {
    s  = s_l[jl] + s_l[64 + jl] + s_l[128 + jl] + s_l[192 + jl];
    s2 = s2_l[jl] + s2_l[64 + jl] + s2_l[128 + jl] + s2_l[192 + jl];
    const float mean = s * (1.f / BATCH);
    const float var  = s2 * (1.f / BATCH) - mean * mean;
    m_l[jl] = mean;
    r_l[jl] = rsqrtf(var + BN_EPS);
  }
  __syncthreads();
  const float mean = m_l[jl];
  const float a    = r_l[jl] * gamma[nf];
  const float c    = beta[nf] - mean * a;
#pragma unroll
  for (int bb = 0; bb < 16; ++bb)
    out[(size_t)nf + (size_t)(bg * 16 + bb) * NADJ * F] = x[bb] * a + c;
}

extern "C" void kernel_launch(void* const* d_in, const int* in_sizes, int n_in,
                              void* d_out, int out_size, void* d_ws,
                              size_t ws_size, hipStream_t stream) {
  const float* input = (const float*)d_in[0];
  const float* adj   = (const float*)d_in[1];
  const float* W     = (const float*)d_in[2];
  const float* gamma = (const float*)d_in[3];
  const float* beta  = (const float*)d_in[4];
  float* out = (float*)d_out;

  ushort* Ocrop = (ushort*)d_ws;  // 64*256*128 bf16 = 4.2 MB

  gcn_ka<<<256, 512, 0, stream>>>(input, adj, W, beta, out, Ocrop);
  gcn_kb<<<512, 256, 0, stream>>>(Ocrop, out, gamma, beta);
}

// Round 18
// 22.981 us; speedup vs baseline: 1.1552x; 1.0227x over previous
//
#include <hip/hip_runtime.h>
#include <hip/hip_bf16.h>

#define BATCH 64
#define NADJ  512
#define F     128
#define CROP0 128
#define CROP1 384
#define CN    256
#define BN_EPS 1e-5f

typedef __attribute__((ext_vector_type(8))) short short8;
typedef __attribute__((ext_vector_type(4))) float f32x4;

__device__ __forceinline__ ushort f2bf(float x) {
  __hip_bfloat16 h = __float2bfloat16(x);  // RNE
  return *reinterpret_cast<ushort*>(&h);
}

__device__ __forceinline__ float bf2f(ushort u) {
  const unsigned v = (unsigned)u << 16;
  float f;
  __builtin_memcpy(&f, &v, 4);
  return f;
}

__device__ __forceinline__ short8 cvt8(const float4 a, const float4 b) {
  short8 r;
  r[0] = (short)f2bf(a.x); r[1] = (short)f2bf(a.y);
  r[2] = (short)f2bf(a.z); r[3] = (short)f2bf(a.w);
  r[4] = (short)f2bf(b.x); r[5] = (short)f2bf(b.y);
  r[6] = (short)f2bf(b.z); r[7] = (short)f2bf(b.w);
  return r;
}

// ---------------------------------------------------------------------------
// KA v18 (R17 + ain double-buffer + early adj cvt).
// 256 blocks x 512 threads, 1 block/CU. Block = (batch b, quarter qt),
// 4 blocks/batch on XCD (b&7). Full S[b] -> LDS stl[128][268].
// One barrier per chunk (5 total, was 8): ain dbuf decouples staging writes
// from compute reads. adj A-operand pre-issued as float4 at entry, converted
// to bf16 short8 in the latency-idle region after W^T staging -> agg loop is
// pure ds_read+MFMA. LDS: wt 34816 + ain 2x17408 + stl 68608 = 138240 B.
// ---------------------------------------------------------------------------
__global__ __launch_bounds__(512, 1) void gcn_ka(
    const float* __restrict__ input, const float* __restrict__ adj,
    const float* __restrict__ W, const float* __restrict__ beta,
    float* __restrict__ out, ushort* __restrict__ Ocrop) {
  const int x = blockIdx.x & 7, y = blockIdx.x >> 3;
  const int b  = ((y >> 2) << 3) | x;  // batch
  const int qt = y & 3;                // quarter (64 n-rows)
  __shared__ ushort wt[128][136];      // W^T [f][i]
  __shared__ ushort ain[2][64][136];   // input chunk dbuf [m][i]
  __shared__ ushort stl[128][268];     // S^T full [f][m], 536B row stride
  const int tid = threadIdx.x;
  const int l = tid & 63, w = tid >> 6;
  const int lr = l & 15, lg = l >> 4;

  // ---- pre-issue agg A-operand: 16 x float4 of adj ----
  const int n0  = qt * 64 + (w & 3) * 16;
  const int wf0 = (w >> 2) * 64;
  const float* a0 =
      adj + ((size_t)b * NADJ + CROP0 + n0 + lr) * NADJ + CROP0;
  float4 xreg[16];
#pragma unroll
  for (int ks = 0; ks < 8; ++ks) {
    const int k0 = ks * 32 + lg * 8;
    xreg[2 * ks]     = *reinterpret_cast<const float4*>(&a0[k0]);
    xreg[2 * ks + 1] = *reinterpret_cast<const float4*>(&a0[k0 + 4]);
  }

  // ---- beta-fill non-crop rows of out ----
  {
    const int gid = blockIdx.x * 512 + tid;
#pragma unroll
    for (int q = 0; q < 4; ++q) {
      const int g2 = gid + q * 131072;
      const int c4 = (g2 & 31) * 4;
      const int rr = (g2 >> 5) & 255;
      const int bb = g2 >> 13;
      const int n  = rr < 128 ? rr : rr + 256;
      const float4 bv =
          *reinterpret_cast<const float4*>(&beta[(size_t)n * F + c4]);
      *reinterpret_cast<float4*>(&out[((size_t)bb * NADJ + n) * F + c4]) = bv;
    }
  }

  // ---- stage W^T ----
  {
    const int i0 = tid & 63;
    const int fq = (tid >> 6) * 16;
#pragma unroll
    for (int ih = 0; ih < 2; ++ih) {
      const int i = i0 + ih * 64;
      const float* wr = &W[(size_t)i * F + fq];
      float4 v[4];
#pragma unroll
      for (int q = 0; q < 4; ++q)
        v[q] = reinterpret_cast<const float4*>(wr)[q];
#pragma unroll
      for (int q = 0; q < 4; ++q) {
        wt[fq + q * 4 + 0][i] = f2bf(v[q].x);
        wt[fq + q * 4 + 1][i] = f2bf(v[q].y);
        wt[fq + q * 4 + 2][i] = f2bf(v[q].z);
        wt[fq + q * 4 + 3][i] = f2bf(v[q].w);
      }
    }
  }

  // ---- issue input chunk-0 prefetch, then convert adj regs (idle slot) ----
  const float* inb = input + ((size_t)b * NADJ + CROP0) * F;
  const int msub = (w & 3) * 16;
  const int sf0  = (w >> 2) * 64;
  const int ml0  = tid >> 5;
  const int ic4  = (tid & 31) * 4;
  float4 pv[4];
#pragma unroll
  for (int q = 0; q < 4; ++q)
    pv[q] = *reinterpret_cast<const float4*>(
        &inb[(size_t)(ml0 + q * 16) * F + ic4]);

  short8 areg[8];  // adj bf16 fragments (agg A-operand), converted early
#pragma unroll
  for (int ks = 0; ks < 8; ++ks)
    areg[ks] = cvt8(xreg[2 * ks], xreg[2 * ks + 1]);

  // ---- write ain[0], single barrier ----
#pragma unroll
  for (int q = 0; q < 4; ++q)
    *reinterpret_cast<ushort4*>(&ain[0][ml0 + q * 16][ic4]) =
        make_ushort4(f2bf(pv[q].x), f2bf(pv[q].y), f2bf(pv[q].z),
                     f2bf(pv[q].w));
  __syncthreads();  // ain[0] + wt visible

  // ---- S-chunks (fully unrolled) + interleaved agg; 1 barrier/chunk ----
  f32x4 acc[4] = {};
#pragma unroll
  for (int cc = 0; cc < 4; ++cc) {
    const int mc = cc * 64;
    // prefetch next input chunk (overlaps everything below)
    if (cc < 3) {
#pragma unroll
      for (int q = 0; q < 4; ++q)
        pv[q] = *reinterpret_cast<const float4*>(
            &inb[(size_t)(mc + 64 + ml0 + q * 16) * F + ic4]);
    }
    // interleaved agg for previous chunk (stl visible since prior barrier)
    if (cc > 0) {
      const int kb0 = mc - 64;
#pragma unroll
      for (int ks2 = 0; ks2 < 2; ++ks2) {
        const int ks = (cc - 1) * 2 + ks2;  // static
        const int k0 = kb0 + ks2 * 32 + lg * 8;
#pragma unroll
        for (int fi = 0; fi < 4; ++fi) {
          const short8 bv =
              *reinterpret_cast<const short8*>(&stl[wf0 + fi * 16 + lr][k0]);
          acc[fi] = __builtin_amdgcn_mfma_f32_16x16x32_bf16(areg[ks], bv,
                                                            acc[fi], 0, 0, 0);
        }
      }
    }
    // S-compute for this chunk from ain[cc&1]
    f32x4 sacc[4] = {};
#pragma unroll
    for (int ks = 0; ks < 4; ++ks) {
      const int k0 = ks * 32 + lg * 8;
      const short8 av =
          *reinterpret_cast<const short8*>(&ain[cc & 1][msub + lr][k0]);
#pragma unroll
      for (int fi = 0; fi < 4; ++fi) {
        const short8 bv =
            *reinterpret_cast<const short8*>(&wt[sf0 + fi * 16 + lr][k0]);
        sacc[fi] =
            __builtin_amdgcn_mfma_f32_16x16x32_bf16(av, bv, sacc[fi], 0, 0, 0);
      }
    }
#pragma unroll
    for (int fi = 0; fi < 4; ++fi)
      *reinterpret_cast<ushort4*>(
          &stl[sf0 + fi * 16 + lr][mc + msub + lg * 4]) =
          make_ushort4(f2bf(sacc[fi][0]), f2bf(sacc[fi][1]),
                       f2bf(sacc[fi][2]), f2bf(sacc[fi][3]));
    // write next chunk into the other ain buffer (no race: disjoint buffer)
    if (cc < 3) {
#pragma unroll
      for (int q = 0; q < 4; ++q)
        *reinterpret_cast<ushort4*>(&ain[(cc + 1) & 1][ml0 + q * 16][ic4]) =
            make_ushort4(f2bf(pv[q].x), f2bf(pv[q].y), f2bf(pv[q].z),
                         f2bf(pv[q].w));
    }
    __syncthreads();  // stl chunk cc + ain[(cc+1)&1] visible
  }

  // ---- final agg chunk (k 192..255) ----
#pragma unroll
  for (int ks2 = 0; ks2 < 2; ++ks2) {
    const int ks = 6 + ks2;
    const int k0 = 192 + ks2 * 32 + lg * 8;
#pragma unroll
    for (int fi = 0; fi < 4; ++fi) {
      const short8 bv =
          *reinterpret_cast<const short8*>(&stl[wf0 + fi * 16 + lr][k0]);
      acc[fi] = __builtin_amdgcn_mfma_f32_16x16x32_bf16(areg[ks], bv, acc[fi],
                                                        0, 0, 0);
    }
  }

  // ---- store Ocrop (bf16): col(f)=lane&15, row(n)=4*(lane>>4)+reg ----
#pragma unroll
  for (int fi = 0; fi < 4; ++fi) {
    const int f = wf0 + fi * 16 + lr;
    const int n = n0 + lg * 4;
#pragma unroll
    for (int r = 0; r < 4; ++r)
      Ocrop[((size_t)b * CN + n + r) * F + f] = f2bf(acc[fi][r]);
  }
}

// ---------------------------------------------------------------------------
// KB: BN stats + normalize crop rows (bf16 Ocrop in, fp32 out).
// ---------------------------------------------------------------------------
__global__ __launch_bounds__(256) void gcn_kb(
    const ushort* __restrict__ Ocrop, float* __restrict__ out,
    const float* __restrict__ gamma, const float* __restrict__ beta) {
  __shared__ float s_l[256], s2_l[256], m_l[64], r_l[64];
  const int tid = threadIdx.x;
  const int jl = tid & 63, bg = tid >> 6;
  const int j  = blockIdx.x * 64 + jl;  // 0..32767 = nl*128+f
  const int nl = j >> 7, f = j & 127;
  const int nf = (CROP0 + nl) * F + f;
  const ushort* p = Ocrop + (size_t)j + (size_t)bg * 16 * CN * F;

  float x[16];
  float s = 0.f, s2 = 0.f;
#pragma unroll
  for (int bb = 0; bb < 16; ++bb) {
    x[bb] = bf2f(p[(size_t)bb * CN * F]);
    s += x[bb];
    s2 += x[bb] * x[bb];
  }
  s_l[tid]  = s;
  s2_l[tid] = s2;
  __syncthreads();
  if (tid < 64) {
    s  = s_l[jl] + s_l[64 + jl] + s_l[128 + jl] + s_l[192 + jl];
    s2 = s2_l[jl] + s2_l[64 + jl] + s2_l[128 + jl] + s2_l[192 + jl];
    const float mean = s * (1.f / BATCH);
    const float var  = s2 * (1.f / BATCH) - mean * mean;
    m_l[jl] = mean;
    r_l[jl] = rsqrtf(var + BN_EPS);
  }
  __syncthreads();
  const float mean = m_l[jl];
  const float a    = r_l[jl] * gamma[nf];
  const float c    = beta[nf] - mean * a;
#pragma unroll
  for (int bb = 0; bb < 16; ++bb)
    out[(size_t)nf + (size_t)(bg * 16 + bb) * NADJ * F] = x[bb] * a + c;
}

extern "C" void kernel_launch(void* const* d_in, const int* in_sizes, int n_in,
                              void* d_out, int out_size, void* d_ws,
                              size_t ws_size, hipStream_t stream) {
  const float* input = (const float*)d_in[0];
  const float* adj   = (const float*)d_in[1];
  const float* W     = (const float*)d_in[2];
  const float* gamma = (const float*)d_in[3];
  const float* beta  = (const float*)d_in[4];
  float* out = (float*)d_out;

  ushort* Ocrop = (ushort*)d_ws;  // 64*256*128 bf16 = 4.2 MB

  gcn_ka<<<256, 512, 0, stream>>>(input, adj, W, beta, out, Ocrop);
  gcn_kb<<<512, 256, 0, stream>>>(Ocrop, out, gamma, beta);
}